// Round 2
// baseline (616.915 us; speedup 1.0000x reference)
//
#include <hip/hip_runtime.h>

#define DEVINL __device__ __forceinline__

typedef unsigned short u16;
typedef unsigned long long u64;
typedef __attribute__((ext_vector_type(8))) short bf16x8;   // 8 bf16 = 4 VGPRs
typedef __attribute__((ext_vector_type(16))) float f32x16;  // 32x32 C/D frag

// problem sizes
#define NB   65536
#define OBSD 128
#define ED   64
#define HD_  128
#define NT   7
#define NA   16

// bf16 weight workspace layout (u16 elements). Wp / out_proj are algebraically
// fused away:  WQP = 0.25*Wq@Wp, WKP = Wk@Wp, WVP = Wv@Wp, wih' = [wih_L | wih_R@Wo]
#define OFF_W1   0        // 64x128
#define OFF_W2   8192     // 64x64
#define OFF_WQP  12288    // 64x128
#define OFF_WKP  20480    // 64x128
#define OFF_WVP  28672    // 64x128
#define OFF_WIH  36864    // 384x128
#define OFF_WHH  86016    // 384x128
#define OFF_POL  135168   // 16x128
#define W_TOTAL  137216
// f32 fused biases appended after bf16 weights:
//   [0..63]=bq' (pre-scaled 0.25), [64..127]=bk', [128..191]=bv', [192..575]=bih'
#define NBIAS    576

DEVINL u16 f2bf(float f) {                 // RNE f32 -> bf16 (finite inputs)
  unsigned u = __float_as_uint(f);
  u += 0x7fff + ((u >> 16) & 1);
  return (u16)(u >> 16);
}
DEVINL float bf2f(u16 h) { return __uint_as_float(((unsigned)h) << 16); }

DEVINL f32x16 mfma(bf16x8 a, bf16x8 b, f32x16 c) {
  return __builtin_amdgcn_mfma_f32_32x32x16_bf16(a, b, c, 0, 0, 0);
}
DEVINL f32x16 zero16() {
  f32x16 z;
#pragma unroll
  for (int i = 0; i < 16; ++i) z[i] = 0.f;
  return z;
}

// A-frag from LDS: 16B as two 8B reads (rows are 8B- but not 16B-aligned)
DEVINL bf16x8 ldsA(const u16* p) {
  union { bf16x8 v; u64 u[2]; } t;
  t.u[0] = *(const u64*)p;
  t.u[1] = *(const u64*)(p + 4);
  return t.v;
}

// A-frag straight from global fp32 (8 consecutive floats, 32B-aligned)
DEVINL bf16x8 gfrag(const float* p) {
  float4 a = ((const float4*)p)[0];
  float4 b = ((const float4*)p)[1];
  bf16x8 r;
  r[0] = (short)f2bf(a.x); r[1] = (short)f2bf(a.y);
  r[2] = (short)f2bf(a.z); r[3] = (short)f2bf(a.w);
  r[4] = (short)f2bf(b.x); r[5] = (short)f2bf(b.y);
  r[6] = (short)f2bf(b.z); r[7] = (short)f2bf(b.w);
  return r;
}

// one 32x32 C tile: A[aRow, k] (LDS, stride S) @ W[n=lane&31 row][k] (global bf16)
template<int KS>
DEVINL f32x16 gemm_acc(const u16* __restrict__ bufA, int S, int aRow, int khalf,
                       const u16* __restrict__ wRow, f32x16 acc) {
  const u16* ap = bufA + aRow * S + khalf;
  const u16* bp = wRow + khalf;
#pragma unroll
  for (int ks = 0; ks < KS; ++ks) {
    bf16x8 a = ldsA(ap + ks * 16);
    bf16x8 b = *(const bf16x8*)(bp + ks * 16);   // 16B aligned
    acc = mfma(a, b, acc);
  }
  return acc;
}

// C-frag -> LDS bf16 with bias (+optional relu). col already includes N offset.
DEVINL void epiLDS(const f32x16& acc, float bias, int rowOff, int col,
                   u16* buf, int S, bool relu) {
#pragma unroll
  for (int r = 0; r < 16; ++r) {
    int row = rowOff + (r & 3) + 8 * (r >> 2);
    float v = acc[r] + bias;
    if (relu) v = fmaxf(v, 0.f);
    buf[row * S + col] = f2bf(v);
  }
}

// 16 consecutive bf16 from LDS (8B aligned) -> 16 floats via 4x u64
DEVINL void rd16(const u16* p, float* o) {
  union { u64 u[4]; u16 s[16]; } t;
  t.u[0] = ((const u64*)p)[0]; t.u[1] = ((const u64*)p)[1];
  t.u[2] = ((const u64*)p)[2]; t.u[3] = ((const u64*)p)[3];
#pragma unroll
  for (int d = 0; d < 16; ++d) o[d] = bf2f(t.s[d]);
}

DEVINL float sigf(float x) { return 1.f / (1.f + __expf(-x)); }

// ---- weight prep: pack + algebraic fusion (fp32 math, bf16 store) ----
__global__ void prep_weights(const float* __restrict__ W1, const float* __restrict__ W2,
                             const float* __restrict__ Wp, const float* __restrict__ bp,
                             const float* __restrict__ inpw, const float* __restrict__ inpb,
                             const float* __restrict__ outpw, const float* __restrict__ outpb,
                             const float* __restrict__ wih, const float* __restrict__ bih,
                             const float* __restrict__ whh, const float* __restrict__ wpol,
                             u16* __restrict__ ws) {
  int i = blockIdx.x * 256 + threadIdx.x;
  if (i < W_TOTAL) {
    float v;
    if (i < OFF_W2)       v = W1[i];
    else if (i < OFF_WQP) v = W2[i - OFF_W2];
    else if (i < OFF_WIH) {
      int o = i - OFF_WQP;            // 3 fused 64x128 mats, 8192 each
      int mat = o >> 13;              // 0=Q 1=K 2=V
      int e = (o >> 7) & 63;
      int h = o & 127;
      const float* wr = inpw + (mat * 64 + e) * 64;
      float acc = 0.f;
#pragma unroll 4
      for (int c = 0; c < 64; ++c) acc += wr[c] * Wp[c * 128 + h];
      v = (mat == 0) ? acc * 0.25f : acc;   // fold 1/sqrt(HD) into q
    } else if (i < OFF_WHH) {
      int o = i - OFF_WIH;
      int g = o >> 7, c = o & 127;
      if (c < 64) v = wih[g * 128 + c];     // h_obs half unchanged
      else {
        int d = c - 64;                     // (wih_R @ Wo)[g][d]
        float acc = 0.f;
#pragma unroll 4
        for (int c2 = 0; c2 < 64; ++c2) acc += wih[g * 128 + 64 + c2] * outpw[c2 * 64 + d];
        v = acc;
      }
    }
    else if (i < OFF_POL) v = whh[i - OFF_WHH];
    else                  v = wpol[i - OFF_POL];
    ws[i] = f2bf(v);
  } else if (i < W_TOTAL + NBIAS) {
    float* wsF = (float*)(ws + W_TOTAL);
    int o = i - W_TOTAL;
    float acc = 0.f;
    if (o < 192) {                          // bq'/bk'/bv' = W{q,k,v}@bp + inpb
      int mat = o >> 6, e = o & 63;
      const float* wr = inpw + (mat * 64 + e) * 64;
      for (int c = 0; c < 64; ++c) acc += wr[c] * bp[c];
      acc += inpb[mat * 64 + e];
      if (mat == 0) acc *= 0.25f;
    } else {                                // bih' = bih + wih_R @ bo
      int g = o - 192;
      for (int c = 0; c < 64; ++c) acc += wih[g * 128 + 64 + c] * outpb[c];
      acc += bih[g];
    }
    wsF[o] = acc;
  }
}

// LDS = 43008 B -> 3 blocks/CU (12 waves/CU). Staging registers are short-lived
// within one loop iteration (issue at top, LDS-write after the K/V MFMAs) so the
// peak live set stays ~135 VGPR < the 168 cap -> no scratch (round-1 lesson).
__global__ __launch_bounds__(256, 3)
void aerial_main(const float* __restrict__ obs, const float* __restrict__ pb,
                 const float* __restrict__ th,
                 const float* __restrict__ b1, const float* __restrict__ b2,
                 const float* __restrict__ bpol, const float* __restrict__ bhh,
                 const u16* __restrict__ wsb,
                 float* __restrict__ outLog, float* __restrict__ outBel,
                 float* __restrict__ outAttn) {
  // strides 132/68: bank step 2 -> 2-way aliasing (free, measured 0 conflicts)
  __shared__ u16 bufT[64 * 132];   // teammate tile (single buffer) -> belief
  __shared__ u16 bufK[64 * 68];    // t1 -> k
  __shared__ u16 bufV[64 * 68];    // q -> v -> ctx
  __shared__ u16 bufHO[64 * 68];   // h_obs (persists to GRU)

  const int tid   = threadIdx.x;
  const int lane  = tid & 63;
  const int m     = lane & 31;
  const int half  = lane >> 5;
  const int khalf = half * 8;
  const int wv    = tid >> 6;
  const int mt    = wv & 1;
  const int nh    = wv >> 1;
  const int aRow  = 32 * mt + m;
  const int rowOff = 32 * mt + 4 * half;
  const int col64 = nh * 32 + m;
  const int gRow0 = blockIdx.x * 64;

  const float* wsF = (const float*)(wsb + W_TOTAL);

  // --- teammate tile staging: regs live only issue->swrite within one iter ---
  float4 sreg[8];
  auto issue = [&](int t) {                 // global -> regs
#pragma unroll
    for (int i = 0; i < 8; ++i) {
      int f4 = tid + i * 256;
      int row = f4 >> 5, c4 = f4 & 31;
      sreg[i] = *(const float4*)(th + ((size_t)(gRow0 + row) * NT + t) * HD_ + c4 * 4);
    }
  };
  auto swrite = [&]() {                     // regs -> LDS bf16
#pragma unroll
    for (int i = 0; i < 8; ++i) {
      int f4 = tid + i * 256;
      int row = f4 >> 5, c4 = f4 & 31;
      ushort4 o;
      o.x = f2bf(sreg[i].x); o.y = f2bf(sreg[i].y);
      o.z = f2bf(sreg[i].z); o.w = f2bf(sreg[i].w);
      *(ushort4*)(bufT + row * 132 + c4 * 4) = o;
    }
  };

  // ---- P0: issue tile0; Q' and A1 with A-frags direct from global fp32 ----
  issue(0);
  { // q = pb @ WQP^T + bq'  (Wp and 0.25 scale folded in) -> bufV
    const float* arow = pb + (size_t)(gRow0 + aRow) * HD_ + khalf;
    const u16* brow = wsb + OFF_WQP + col64 * 128 + khalf;
    f32x16 acc = zero16();
#pragma unroll
    for (int ks = 0; ks < 8; ++ks)
      acc = mfma(gfrag(arow + ks * 16), *(const bf16x8*)(brow + ks * 16), acc);
    epiLDS(acc, wsF[col64], rowOff, col64, bufV, 68, false);
  }
  { // t1 = relu(obs @ W1^T + b1) -> bufK
    const float* arow = obs + (size_t)(gRow0 + aRow) * OBSD + khalf;
    const u16* brow = wsb + OFF_W1 + col64 * 128 + khalf;
    f32x16 acc = zero16();
#pragma unroll
    for (int ks = 0; ks < 8; ++ks)
      acc = mfma(gfrag(arow + ks * 16), *(const bf16x8*)(brow + ks * 16), acc);
    epiLDS(acc, b1[col64], rowOff, col64, bufK, 68, true);
  }
  swrite();                                  // tile0 -> bufT (vmcnt long met)
  __syncthreads();

  // ---- P1: A2 + q->regs; no barrier (loop's barrier A covers the handoff) ----
  { // h_obs = relu(t1 @ W2^T + b2) -> bufHO
    f32x16 acc = gemm_acc<4>(bufK, 68, aRow, khalf, wsb + OFF_W2 + col64 * 64, zero16());
    epiLDS(acc, b2[col64], rowOff, col64, bufHO, 68, true);
  }
  const int b  = tid >> 2;                   // attention thread = (row, head)
  const int hh = tid & 3;
  float qreg[16];
  rd16(bufV + b * 68 + hh * 16, qreg);

  // ---- teammate loop: 2 barriers/iter, stage overlapped with K/V MFMAs ----
  const u16* bKp = wsb + OFF_WKP + col64 * 128 + khalf;
  const u16* bVp = wsb + OFF_WVP + col64 * 128 + khalf;
  const float bkF = wsF[64 + col64];
  const float bvF = wsF[128 + col64];
  float ctx[16];
#pragma unroll
  for (int d = 0; d < 16; ++d) ctx[d] = 0.f;
  float l = 0.f, parr[NT];

#pragma unroll
  for (int t = 0; t < NT; ++t) {
    if (t + 1 < NT) issue(t + 1);            // loads in flight across barrier A
    bf16x8 af[8];
#pragma unroll
    for (int ks = 0; ks < 8; ++ks) af[ks] = ldsA(bufT + aRow * 132 + ks * 16 + khalf);
    __syncthreads();                         // A: tile reads done, bufK/V free
    { // k = tile @ WKP^T + bk'  (sequential accs keep VGPR peak low)
      f32x16 aK = zero16();
#pragma unroll
      for (int ks = 0; ks < 8; ++ks) aK = mfma(af[ks], *(const bf16x8*)(bKp + ks * 16), aK);
      epiLDS(aK, bkF, rowOff, col64, bufK, 68, false);
    }
    { // v = tile @ WVP^T + bv'
      f32x16 aV = zero16();
#pragma unroll
      for (int ks = 0; ks < 8; ++ks) aV = mfma(af[ks], *(const bf16x8*)(bVp + ks * 16), aV);
      epiLDS(aV, bvF, rowOff, col64, bufV, 68, false);
    }
    if (t + 1 < NT) swrite();                // tile t+1 -> bufT
    __syncthreads();                         // B: k/v ready, tile t+1 ready
    { // score + PV (|s| small -> exp w/o max-subtraction is exact)
      float kv[16];
      rd16(bufK + b * 68 + hh * 16, kv);
      float s = 0.f;
#pragma unroll
      for (int d = 0; d < 16; ++d) s += qreg[d] * kv[d];
      float p = __expf(s);
      l += p; parr[t] = p;
      rd16(bufV + b * 68 + hh * 16, kv);
#pragma unroll
      for (int d = 0; d < 16; ++d) ctx[d] += p * kv[d];
    }
  }

  // ---- P2: attn weights out + normalized ctx -> bufV (own addresses, no race) ----
  {
    float linv = 1.f / l;
#pragma unroll
    for (int t = 0; t < NT; ++t) {
      float a = parr[t] * linv;
      a += __shfl_xor(a, 1);
      a += __shfl_xor(a, 2);
      if (hh == 0) outAttn[(size_t)(gRow0 + b) * NT + t] = a * 0.25f;
    }
#pragma unroll
    for (int d = 0; d < 16; ++d) bufV[b * 68 + hh * 16 + d] = f2bf(ctx[d] * linv);
  }
  __syncthreads();

  // ---- P3: GRU (out_proj folded into wih'); pb from global ----
  bf16x8 ax[8], apb[8];
#pragma unroll
  for (int ks = 0; ks < 4; ++ks) ax[ks]     = ldsA(bufHO + aRow * 68 + ks * 16 + khalf);
#pragma unroll
  for (int ks = 0; ks < 4; ++ks) ax[4 + ks] = ldsA(bufV  + aRow * 68 + ks * 16 + khalf);
  const float* pbrow = pb + (size_t)(gRow0 + aRow) * HD_ + khalf;
#pragma unroll
  for (int ks = 0; ks < 8; ++ks) apb[ks] = gfrag(pbrow + ks * 16);

#pragma unroll
  for (int hj = 0; hj < 2; ++hj) {
    int j = nh * 32 + hj * 64 + m;           // gate output index 0..127
    const u16* wr = wsb + OFF_WIH + (size_t)(0 * HD_ + j) * 128;
    const u16* wz = wsb + OFF_WIH + (size_t)(1 * HD_ + j) * 128;
    const u16* wn = wsb + OFF_WIH + (size_t)(2 * HD_ + j) * 128;
    const u16* vr = wsb + OFF_WHH + (size_t)(0 * HD_ + j) * 128;
    const u16* vz = wsb + OFF_WHH + (size_t)(1 * HD_ + j) * 128;
    const u16* vn = wsb + OFF_WHH + (size_t)(2 * HD_ + j) * 128;
    f32x16 ar = zero16(), az = zero16(), ai = zero16(), ah = zero16();
#pragma unroll
    for (int ks = 0; ks < 8; ++ks) {
      int ko = ks * 16 + khalf;
      ar = mfma(ax[ks], *(const bf16x8*)(wr + ko), ar);
      az = mfma(ax[ks], *(const bf16x8*)(wz + ko), az);
      ai = mfma(ax[ks], *(const bf16x8*)(wn + ko), ai);
    }
#pragma unroll
    for (int ks = 0; ks < 8; ++ks) {
      int ko = ks * 16 + khalf;
      ar = mfma(apb[ks], *(const bf16x8*)(vr + ko), ar);
      az = mfma(apb[ks], *(const bf16x8*)(vz + ko), az);
      ah = mfma(apb[ks], *(const bf16x8*)(vn + ko), ah);
    }
    float br_ = wsF[192 + j] + bhh[j];
    float bz_ = wsF[192 + 128 + j] + bhh[128 + j];
    float bi_ = wsF[192 + 256 + j];
    float bh_ = bhh[256 + j];
#pragma unroll
    for (int r = 0; r < 16; ++r) {
      int row = rowOff + (r & 3) + 8 * (r >> 2);
      float rr = sigf(ar[r] + br_);
      float zz = sigf(az[r] + bz_);
      float xn = ai[r] + bi_ + rr * (ah[r] + bh_);
      xn = fminf(fmaxf(xn, -15.f), 15.f);
      float tt = __expf(2.f * xn);
      float nn = (tt - 1.f) / (tt + 1.f);    // tanh
      float pv = pb[(size_t)(gRow0 + row) * HD_ + j];   // fp32, cache-served
      float bel = (1.f - zz) * nn + zz * pv;
      outBel[(size_t)(gRow0 + row) * HD_ + j] = bel;
      bufT[row * 132 + j] = f2bf(bel);       // tile long dead
    }
  }
  __syncthreads();

  // ---- P4: policy head (waves nh==0 only; N=16 < tile width 32) ----
  if (nh == 0) {
    int nclamp = (m < 16) ? m : 15;
    f32x16 acc = gemm_acc<8>(bufT, 132, aRow, khalf, wsb + OFF_POL + nclamp * 128, zero16());
    if (m < 16) {
      float bv = bpol[m];
#pragma unroll
      for (int r = 0; r < 16; ++r) {
        int row = rowOff + (r & 3) + 8 * (r >> 2);
        outLog[(size_t)(gRow0 + row) * NA + m] = acc[r] + bv;
      }
    }
  }
}

extern "C" void kernel_launch(void* const* d_in, const int* in_sizes, int n_in,
                              void* d_out, int out_size, void* d_ws, size_t ws_size,
                              hipStream_t stream) {
  const float* obs   = (const float*)d_in[0];
  const float* pb    = (const float*)d_in[1];
  const float* th    = (const float*)d_in[2];
  const float* W1    = (const float*)d_in[3];
  const float* b1    = (const float*)d_in[4];
  const float* W2    = (const float*)d_in[5];
  const float* b2    = (const float*)d_in[6];
  const float* Wp    = (const float*)d_in[7];
  const float* bp    = (const float*)d_in[8];
  const float* inpw  = (const float*)d_in[9];
  const float* inpb  = (const float*)d_in[10];
  const float* outpw = (const float*)d_in[11];
  const float* outpb = (const float*)d_in[12];
  const float* wih   = (const float*)d_in[13];
  const float* whh   = (const float*)d_in[14];
  const float* bih   = (const float*)d_in[15];
  const float* bhh   = (const float*)d_in[16];
  const float* wpol  = (const float*)d_in[17];
  const float* bpol  = (const float*)d_in[18];

  u16* wsb = (u16*)d_ws;                     // 274432 B bf16 weights + 2304 B f32 biases
  float* outLog  = (float*)d_out;
  float* outBel  = outLog + (size_t)NB * NA;
  float* outAttn = outBel + (size_t)NB * HD_;

  prep_weights<<<(W_TOTAL + NBIAS + 255) / 256, 256, 0, stream>>>(
      W1, W2, Wp, bp, inpw, inpb, outpw, outpb, wih, bih, whh, wpol, wsb);
  aerial_main<<<NB / 64, 256, 0, stream>>>(obs, pb, th, b1, b2, bpol, bhh, wsb,
                                           outLog, outBel, outAttn);
}

// Round 3
// 483.929 us; speedup vs baseline: 1.2748x; 1.2748x over previous
//
#include <hip/hip_runtime.h>

#define DEVINL __device__ __forceinline__

typedef unsigned short u16;
typedef unsigned long long u64;
typedef __attribute__((ext_vector_type(8))) short bf16x8;   // 8 bf16 = 4 VGPRs
typedef __attribute__((ext_vector_type(16))) float f32x16;  // 32x32 C/D frag

// problem sizes
#define NB   65536
#define OBSD 128
#define ED   64
#define HD_  128
#define NT   7
#define NA   16

// bf16 weight workspace layout (u16 elements). Wp / out_proj are algebraically
// fused away:  WQP = 0.25*Wq@Wp, WKP = Wk@Wp, WVP = Wv@Wp, wih' = [wih_L | wih_R@Wo]
#define OFF_W1   0        // 64x128
#define OFF_W2   8192     // 64x64
#define OFF_WQP  12288    // 64x128
#define OFF_WKP  20480    // 64x128
#define OFF_WVP  28672    // 64x128
#define OFF_WIH  36864    // 384x128
#define OFF_WHH  86016    // 384x128
#define OFF_POL  135168   // 16x128
#define W_TOTAL  137216
// f32 fused biases appended after bf16 weights:
//   [0..63]=bq' (pre-scaled 0.25), [64..127]=bk', [128..191]=bv', [192..575]=bih'
#define NBIAS    576

DEVINL u16 f2bf(float f) {                 // RNE f32 -> bf16 (finite inputs)
  unsigned u = __float_as_uint(f);
  u += 0x7fff + ((u >> 16) & 1);
  return (u16)(u >> 16);
}
DEVINL float bf2f(u16 h) { return __uint_as_float(((unsigned)h) << 16); }

DEVINL f32x16 mfma(bf16x8 a, bf16x8 b, f32x16 c) {
  return __builtin_amdgcn_mfma_f32_32x32x16_bf16(a, b, c, 0, 0, 0);
}
DEVINL f32x16 zero16() {
  f32x16 z;
#pragma unroll
  for (int i = 0; i < 16; ++i) z[i] = 0.f;
  return z;
}

// A-frag from LDS: 16B as two 8B reads (rows are 8B- but not 16B-aligned)
DEVINL bf16x8 ldsA(const u16* p) {
  union { bf16x8 v; u64 u[2]; } t;
  t.u[0] = *(const u64*)p;
  t.u[1] = *(const u64*)(p + 4);
  return t.v;
}

// one 32x32 C tile: A[aRow, k] (LDS, stride S) @ W[n=lane&31 row][k] (global bf16)
template<int KS>
DEVINL f32x16 gemm_acc(const u16* __restrict__ bufA, int S, int aRow, int khalf,
                       const u16* __restrict__ wRow, f32x16 acc) {
  const u16* ap = bufA + aRow * S + khalf;
  const u16* bp = wRow + khalf;
#pragma unroll
  for (int ks = 0; ks < KS; ++ks) {
    bf16x8 a = ldsA(ap + ks * 16);
    bf16x8 b = *(const bf16x8*)(bp + ks * 16);   // 16B aligned
    acc = mfma(a, b, acc);
  }
  return acc;
}

// C-frag -> LDS bf16 with bias (+optional relu). col already includes N offset.
DEVINL void epiLDS(const f32x16& acc, float bias, int rowOff, int col,
                   u16* buf, int S, bool relu) {
#pragma unroll
  for (int r = 0; r < 16; ++r) {
    int row = rowOff + (r & 3) + 8 * (r >> 2);
    float v = acc[r] + bias;
    if (relu) v = fmaxf(v, 0.f);
    buf[row * S + col] = f2bf(v);
  }
}

// 16 consecutive bf16 from LDS (8B aligned) -> 16 floats via 4x u64
DEVINL void rd16(const u16* p, float* o) {
  union { u64 u[4]; u16 s[16]; } t;
  t.u[0] = ((const u64*)p)[0]; t.u[1] = ((const u64*)p)[1];
  t.u[2] = ((const u64*)p)[2]; t.u[3] = ((const u64*)p)[3];
#pragma unroll
  for (int d = 0; d < 16; ++d) o[d] = bf2f(t.s[d]);
}

DEVINL float sigf(float x) { return 1.f / (1.f + __expf(-x)); }

// ---- weight prep: pack + algebraic fusion (fp32 math, bf16 store) ----
__global__ void prep_weights(const float* __restrict__ W1, const float* __restrict__ W2,
                             const float* __restrict__ Wp, const float* __restrict__ bp,
                             const float* __restrict__ inpw, const float* __restrict__ inpb,
                             const float* __restrict__ outpw, const float* __restrict__ outpb,
                             const float* __restrict__ wih, const float* __restrict__ bih,
                             const float* __restrict__ whh, const float* __restrict__ wpol,
                             u16* __restrict__ ws) {
  int i = blockIdx.x * 256 + threadIdx.x;
  if (i < W_TOTAL) {
    float v;
    if (i < OFF_W2)       v = W1[i];
    else if (i < OFF_WQP) v = W2[i - OFF_W2];
    else if (i < OFF_WIH) {
      int o = i - OFF_WQP;            // 3 fused 64x128 mats, 8192 each
      int mat = o >> 13;              // 0=Q 1=K 2=V
      int e = (o >> 7) & 63;
      int h = o & 127;
      const float* wr = inpw + (mat * 64 + e) * 64;
      float acc = 0.f;
#pragma unroll 4
      for (int c = 0; c < 64; ++c) acc += wr[c] * Wp[c * 128 + h];
      v = (mat == 0) ? acc * 0.25f : acc;   // fold 1/sqrt(HD) into q
    } else if (i < OFF_WHH) {
      int o = i - OFF_WIH;
      int g = o >> 7, c = o & 127;
      if (c < 64) v = wih[g * 128 + c];     // h_obs half unchanged
      else {
        int d = c - 64;                     // (wih_R @ Wo)[g][d]
        float acc = 0.f;
#pragma unroll 4
        for (int c2 = 0; c2 < 64; ++c2) acc += wih[g * 128 + 64 + c2] * outpw[c2 * 64 + d];
        v = acc;
      }
    }
    else if (i < OFF_POL) v = whh[i - OFF_WHH];
    else                  v = wpol[i - OFF_POL];
    ws[i] = f2bf(v);
  } else if (i < W_TOTAL + NBIAS) {
    float* wsF = (float*)(ws + W_TOTAL);
    int o = i - W_TOTAL;
    float acc = 0.f;
    if (o < 192) {                          // bq'/bk'/bv' = W{q,k,v}@bp + inpb
      int mat = o >> 6, e = o & 63;
      const float* wr = inpw + (mat * 64 + e) * 64;
      for (int c = 0; c < 64; ++c) acc += wr[c] * bp[c];
      acc += inpb[mat * 64 + e];
      if (mat == 0) acc *= 0.25f;
    } else {                                // bih' = bih + wih_R @ bo
      int g = o - 192;
      for (int c = 0; c < 64; ++c) acc += wih[g * 128 + 64 + c] * outpb[c];
      acc += bih[g];
    }
    wsF[o] = acc;
  }
}

// Round-0 skeleton (proven no-spill: (256,2), LDS staging, 59904 B LDS) with the
// verified algebraic fusion grafted in. Loop: 2 barriers/iter (was 5), 18 total.
__global__ __launch_bounds__(256, 2)
void aerial_main(const float* __restrict__ obs, const float* __restrict__ pb,
                 const float* __restrict__ th,
                 const float* __restrict__ b1, const float* __restrict__ b2,
                 const float* __restrict__ bpol, const float* __restrict__ bhh,
                 const u16* __restrict__ wsb,
                 float* __restrict__ outLog, float* __restrict__ outBel,
                 float* __restrict__ outAttn) {
  // strides 132/68: word-stride 66/34 -> bank step 2 -> 2-way aliasing (free)
  __shared__ u16 bufP[64 * 132];   // prev_belief bf16 (persists to GRU)
  __shared__ u16 bufB[64 * 132];   // obs -> teammate tiles -> belief
  __shared__ u16 bufH1[64 * 68];   // t1 -> v -> ctx
  __shared__ u16 bufHO[64 * 68];   // h_obs (persists to GRU)
  __shared__ u16 bufQ[64 * 68];    // q -> k

  const int tid   = threadIdx.x;
  const int lane  = tid & 63;
  const int m     = lane & 31;
  const int half  = lane >> 5;
  const int khalf = half * 8;
  const int wv    = tid >> 6;
  const int mt    = wv & 1;        // M-tile (rows 32*mt..)
  const int nh    = wv >> 1;       // N-half
  const int aRow  = 32 * mt + m;
  const int rowOff = 32 * mt + 4 * half;
  const int col64 = nh * 32 + m;   // column in 64-wide stages
  const int gRow0 = blockIdx.x * 64;

  const float* wsF = (const float*)(wsb + W_TOTAL);

  // stage 64x128 f32 tile -> bf16 LDS (stride 132), coalesced float4
  auto stage = [&](const float* src, int srcStride, u16* dst) {
#pragma unroll
    for (int i = 0; i < 8; ++i) {
      int f4 = tid + i * 256;          // 0..2047
      int row = f4 >> 5;               // 32 float4 per row
      int c4  = f4 & 31;
      float4 v = *(const float4*)(src + (size_t)row * srcStride + c4 * 4);
      ushort4 o;
      o.x = f2bf(v.x); o.y = f2bf(v.y); o.z = f2bf(v.z); o.w = f2bf(v.w);
      *(ushort4*)(dst + row * 132 + c4 * 4) = o;
    }
  };

  // ---- phase 0: stage obs + prev_belief ----
  stage(obs + (size_t)gRow0 * OBSD, OBSD, bufB);
  stage(pb  + (size_t)gRow0 * HD_,  HD_,  bufP);
  __syncthreads();

  { // A1: relu(obs @ W1^T + b1) -> t1
    f32x16 acc = gemm_acc<8>(bufB, 132, aRow, khalf, wsb + OFF_W1 + col64 * 128, zero16());
    epiLDS(acc, b1[col64], rowOff, col64, bufH1, 68, true);
  }
  { // Q': pb @ WQP^T + bq'  (Wp, Wq and 0.25 scale all folded) -> q
    f32x16 acc = gemm_acc<8>(bufP, 132, aRow, khalf, wsb + OFF_WQP + col64 * 128, zero16());
    epiLDS(acc, wsF[col64], rowOff, col64, bufQ, 68, false);
  }
  __syncthreads();

  { // A2: relu(t1 @ W2^T + b2) -> h_obs
    f32x16 acc = gemm_acc<4>(bufH1, 68, aRow, khalf, wsb + OFF_W2 + col64 * 64, zero16());
    epiLDS(acc, b2[col64], rowOff, col64, bufHO, 68, true);
  }
  // q -> regs (before loop's first barrier; all waves read before any k-write)
  const int b  = tid >> 2;             // attention thread = (row, head)
  const int hh = tid & 3;
  float qreg[16];
  rd16(bufQ + b * 68 + hh * 16, qreg);

  const u16* bKp = wsb + OFF_WKP + col64 * 128 + khalf;
  const u16* bVp = wsb + OFF_WVP + col64 * 128 + khalf;
  const float bkF = wsF[64 + col64];
  const float bvF = wsF[128 + col64];
  float ctx[16];
#pragma unroll
  for (int d = 0; d < 16; ++d) ctx[d] = 0.f;
  float l = 0.f, parr[NT];

  // ---- teammate loop: stage, {K',V'} sharing A-frags, score+PV ----
#pragma unroll
  for (int t = 0; t < NT; ++t) {
    stage(th + (size_t)gRow0 * (NT * HD_) + t * HD_, NT * HD_, bufB);
    __syncthreads();
    {
      bf16x8 af[8];
#pragma unroll
      for (int ks = 0; ks < 8; ++ks) af[ks] = ldsA(bufB + aRow * 132 + ks * 16 + khalf);
      f32x16 aK = zero16(), aV = zero16();
#pragma unroll
      for (int ks = 0; ks < 8; ++ks) {   // two independent 8-deep chains
        aK = mfma(af[ks], *(const bf16x8*)(bKp + ks * 16), aK);
        aV = mfma(af[ks], *(const bf16x8*)(bVp + ks * 16), aV);
      }
      epiLDS(aK, bkF, rowOff, col64, bufQ, 68, false);   // k
      epiLDS(aV, bvF, rowOff, col64, bufH1, 68, false);  // v
    }
    __syncthreads();
    { // score + PV (|s| small -> exp w/o max-subtraction is exact)
      float kv[16];
      rd16(bufQ + b * 68 + hh * 16, kv);
      float s = 0.f;
#pragma unroll
      for (int d = 0; d < 16; ++d) s += qreg[d] * kv[d];
      float p = __expf(s);
      l += p; parr[t] = p;
      rd16(bufH1 + b * 68 + hh * 16, kv);
#pragma unroll
      for (int d = 0; d < 16; ++d) ctx[d] += p * kv[d];
    }
  }

  { // attn_weights (mean over heads) + normalized ctx -> bufH1
    float linv = 1.f / l;
#pragma unroll
    for (int t = 0; t < NT; ++t) {
      float a = parr[t] * linv;
      a += __shfl_xor(a, 1);
      a += __shfl_xor(a, 2);
      if (hh == 0) outAttn[(size_t)(gRow0 + b) * NT + t] = a * 0.25f;
    }
#pragma unroll
    for (int d = 0; d < 16; ++d) bufH1[b * 68 + hh * 16 + d] = f2bf(ctx[d] * linv);
  }
  __syncthreads();

  // ---- GRU (out_proj folded into wih'): gates via MFMA, epilogue in-register ----
  bf16x8 ax[8], apb[8];                // x = [h_obs | ctx], pb
#pragma unroll
  for (int ks = 0; ks < 4; ++ks) ax[ks]     = ldsA(bufHO + aRow * 68 + ks * 16 + khalf);
#pragma unroll
  for (int ks = 0; ks < 4; ++ks) ax[4 + ks] = ldsA(bufH1 + aRow * 68 + ks * 16 + khalf);
#pragma unroll
  for (int ks = 0; ks < 8; ++ks) apb[ks]    = ldsA(bufP  + aRow * 132 + ks * 16 + khalf);

#pragma unroll
  for (int hj = 0; hj < 2; ++hj) {
    int j = nh * 32 + hj * 64 + m;     // gate output index 0..127
    const u16* wr = wsb + OFF_WIH + (size_t)(0 * HD_ + j) * 128;
    const u16* wz = wsb + OFF_WIH + (size_t)(1 * HD_ + j) * 128;
    const u16* wn = wsb + OFF_WIH + (size_t)(2 * HD_ + j) * 128;
    const u16* vr = wsb + OFF_WHH + (size_t)(0 * HD_ + j) * 128;
    const u16* vz = wsb + OFF_WHH + (size_t)(1 * HD_ + j) * 128;
    const u16* vn = wsb + OFF_WHH + (size_t)(2 * HD_ + j) * 128;
    f32x16 ar = zero16(), az = zero16(), ai = zero16(), ah = zero16();
#pragma unroll
    for (int ks = 0; ks < 8; ++ks) {   // 3 independent MFMA chains
      int ko = ks * 16 + khalf;
      ar = mfma(ax[ks], *(const bf16x8*)(wr + ko), ar);
      az = mfma(ax[ks], *(const bf16x8*)(wz + ko), az);
      ai = mfma(ax[ks], *(const bf16x8*)(wn + ko), ai);
    }
#pragma unroll
    for (int ks = 0; ks < 8; ++ks) {
      int ko = ks * 16 + khalf;
      ar = mfma(apb[ks], *(const bf16x8*)(vr + ko), ar);
      az = mfma(apb[ks], *(const bf16x8*)(vz + ko), az);
      ah = mfma(apb[ks], *(const bf16x8*)(vn + ko), ah);
    }
    float br_ = wsF[192 + j] + bhh[j];
    float bz_ = wsF[192 + 128 + j] + bhh[128 + j];
    float bi_ = wsF[192 + 256 + j];
    float bh_ = bhh[256 + j];
#pragma unroll
    for (int r = 0; r < 16; ++r) {
      int row = rowOff + (r & 3) + 8 * (r >> 2);
      float rr = sigf(ar[r] + br_);
      float zz = sigf(az[r] + bz_);
      float xn = ai[r] + bi_ + rr * (ah[r] + bh_);
      xn = fminf(fmaxf(xn, -15.f), 15.f);
      float tt = __expf(2.f * xn);
      float nn = (tt - 1.f) / (tt + 1.f);  // tanh
      float pv = bf2f(bufP[row * 132 + j]);
      float bel = (1.f - zz) * nn + zz * pv;
      outBel[(size_t)(gRow0 + row) * HD_ + j] = bel;
      bufB[row * 132 + j] = f2bf(bel);     // teammate tile long dead
    }
  }
  __syncthreads();

  // ---- policy head (waves nh==0 only; N=16 < tile width 32) ----
  if (nh == 0) {
    int nclamp = (m < 16) ? m : 15;        // clamp B-row for lanes past N
    f32x16 acc = gemm_acc<8>(bufB, 132, aRow, khalf, wsb + OFF_POL + nclamp * 128, zero16());
    if (m < 16) {
      float bv = bpol[m];
#pragma unroll
      for (int r = 0; r < 16; ++r) {
        int row = rowOff + (r & 3) + 8 * (r >> 2);
        outLog[(size_t)(gRow0 + row) * NA + m] = acc[r] + bv;
      }
    }
  }
}

extern "C" void kernel_launch(void* const* d_in, const int* in_sizes, int n_in,
                              void* d_out, int out_size, void* d_ws, size_t ws_size,
                              hipStream_t stream) {
  const float* obs   = (const float*)d_in[0];
  const float* pb    = (const float*)d_in[1];
  const float* th    = (const float*)d_in[2];
  const float* W1    = (const float*)d_in[3];
  const float* b1    = (const float*)d_in[4];
  const float* W2    = (const float*)d_in[5];
  const float* b2    = (const float*)d_in[6];
  const float* Wp    = (const float*)d_in[7];
  const float* bp    = (const float*)d_in[8];
  const float* inpw  = (const float*)d_in[9];
  const float* inpb  = (const float*)d_in[10];
  const float* outpw = (const float*)d_in[11];
  const float* outpb = (const float*)d_in[12];
  const float* wih   = (const float*)d_in[13];
  const float* whh   = (const float*)d_in[14];
  const float* bih   = (const float*)d_in[15];
  const float* bhh   = (const float*)d_in[16];
  const float* wpol  = (const float*)d_in[17];
  const float* bpol  = (const float*)d_in[18];

  u16* wsb = (u16*)d_ws;                     // 274432 B bf16 weights + 2304 B f32 biases
  float* outLog  = (float*)d_out;
  float* outBel  = outLog + (size_t)NB * NA;
  float* outAttn = outBel + (size_t)NB * HD_;

  prep_weights<<<(W_TOTAL + NBIAS + 255) / 256, 256, 0, stream>>>(
      W1, W2, Wp, bp, inpw, inpb, outpw, outpb, wih, bih, whh, wpol, wsb);
  aerial_main<<<NB / 64, 256, 0, stream>>>(obs, pb, th, b1, b2, bpol, bhh, wsb,
                                           outLog, outBel, outAttn);
}

// Round 4
// 482.991 us; speedup vs baseline: 1.2773x; 1.0019x over previous
//
#include <hip/hip_runtime.h>

#define DEVINL __device__ __forceinline__

typedef unsigned short u16;
typedef unsigned long long u64;
typedef __attribute__((ext_vector_type(8))) short bf16x8;   // 8 bf16 = 4 VGPRs
typedef __attribute__((ext_vector_type(16))) float f32x16;  // 32x32 C/D frag

// problem sizes
#define NB   65536
#define OBSD 128
#define ED   64
#define HD_  128
#define NT   7
#define NA   16

// bf16 weight workspace layout (u16 elements). Wp / out_proj are algebraically
// fused away:  WQP = 0.25*Wq@Wp, WKP = Wk@Wp, WVP = Wv@Wp, wih' = [wih_L | wih_R@Wo]
#define OFF_W1   0        // 64x128
#define OFF_W2   8192     // 64x64
#define OFF_WQP  12288    // 64x128
#define OFF_WKP  20480    // 64x128
#define OFF_WVP  28672    // 64x128
#define OFF_WIH  36864    // 384x128
#define OFF_WHH  86016    // 384x128
#define OFF_POL  135168   // 16x128
#define W_TOTAL  137216
// f32 fused biases appended after bf16 weights:
//   [0..63]=bq' (pre-scaled 0.25), [64..127]=bk', [128..191]=bv', [192..575]=bih'
#define NBIAS    576

DEVINL u16 f2bf(float f) {                 // RNE f32 -> bf16 (finite inputs)
  unsigned u = __float_as_uint(f);
  u += 0x7fff + ((u >> 16) & 1);
  return (u16)(u >> 16);
}
DEVINL float bf2f(u16 h) { return __uint_as_float(((unsigned)h) << 16); }

DEVINL f32x16 mfma(bf16x8 a, bf16x8 b, f32x16 c) {
  return __builtin_amdgcn_mfma_f32_32x32x16_bf16(a, b, c, 0, 0, 0);
}
DEVINL f32x16 zero16() {
  f32x16 z;
#pragma unroll
  for (int i = 0; i < 16; ++i) z[i] = 0.f;
  return z;
}

// A-frag from LDS: 16B as two 8B reads (rows are 8B- but not 16B-aligned)
DEVINL bf16x8 ldsA(const u16* p) {
  union { bf16x8 v; u64 u[2]; } t;
  t.u[0] = *(const u64*)p;
  t.u[1] = *(const u64*)(p + 4);
  return t.v;
}

// one 32x32 C tile: A[aRow, k] (LDS, stride S) @ W[n=lane&31 row][k] (global bf16)
template<int KS>
DEVINL f32x16 gemm_acc(const u16* __restrict__ bufA, int S, int aRow, int khalf,
                       const u16* __restrict__ wRow, f32x16 acc) {
  const u16* ap = bufA + aRow * S + khalf;
  const u16* bp = wRow + khalf;
#pragma unroll
  for (int ks = 0; ks < KS; ++ks) {
    bf16x8 a = ldsA(ap + ks * 16);
    bf16x8 b = *(const bf16x8*)(bp + ks * 16);   // 16B aligned
    acc = mfma(a, b, acc);
  }
  return acc;
}

// C-frag -> LDS bf16 with bias (+optional relu). col already includes N offset.
DEVINL void epiLDS(const f32x16& acc, float bias, int rowOff, int col,
                   u16* buf, int S, bool relu) {
#pragma unroll
  for (int r = 0; r < 16; ++r) {
    int row = rowOff + (r & 3) + 8 * (r >> 2);
    float v = acc[r] + bias;
    if (relu) v = fmaxf(v, 0.f);
    buf[row * S + col] = f2bf(v);
  }
}

// 16 consecutive bf16 from LDS (8B aligned) -> 16 floats via 4x u64
DEVINL void rd16(const u16* p, float* o) {
  union { u64 u[4]; u16 s[16]; } t;
  t.u[0] = ((const u64*)p)[0]; t.u[1] = ((const u64*)p)[1];
  t.u[2] = ((const u64*)p)[2]; t.u[3] = ((const u64*)p)[3];
#pragma unroll
  for (int d = 0; d < 16; ++d) o[d] = bf2f(t.s[d]);
}

DEVINL float sigf(float x) { return 1.f / (1.f + __expf(-x)); }

// ---- weight prep: pack + algebraic fusion (fp32 math, bf16 store) ----
__global__ void prep_weights(const float* __restrict__ W1, const float* __restrict__ W2,
                             const float* __restrict__ Wp, const float* __restrict__ bp,
                             const float* __restrict__ inpw, const float* __restrict__ inpb,
                             const float* __restrict__ outpw, const float* __restrict__ outpb,
                             const float* __restrict__ wih, const float* __restrict__ bih,
                             const float* __restrict__ whh, const float* __restrict__ wpol,
                             u16* __restrict__ ws) {
  int i = blockIdx.x * 256 + threadIdx.x;
  if (i < W_TOTAL) {
    float v;
    if (i < OFF_W2)       v = W1[i];
    else if (i < OFF_WQP) v = W2[i - OFF_W2];
    else if (i < OFF_WIH) {
      int o = i - OFF_WQP;            // 3 fused 64x128 mats, 8192 each
      int mat = o >> 13;              // 0=Q 1=K 2=V
      int e = (o >> 7) & 63;
      int h = o & 127;
      const float* wr = inpw + (mat * 64 + e) * 64;
      float acc = 0.f;
#pragma unroll 4
      for (int c = 0; c < 64; ++c) acc += wr[c] * Wp[c * 128 + h];
      v = (mat == 0) ? acc * 0.25f : acc;   // fold 1/sqrt(HD) into q
    } else if (i < OFF_WHH) {
      int o = i - OFF_WIH;
      int g = o >> 7, c = o & 127;
      if (c < 64) v = wih[g * 128 + c];     // h_obs half unchanged
      else {
        int d = c - 64;                     // (wih_R @ Wo)[g][d]
        float acc = 0.f;
#pragma unroll 4
        for (int c2 = 0; c2 < 64; ++c2) acc += wih[g * 128 + 64 + c2] * outpw[c2 * 64 + d];
        v = acc;
      }
    }
    else if (i < OFF_POL) v = whh[i - OFF_WHH];
    else                  v = wpol[i - OFF_POL];
    ws[i] = f2bf(v);
  } else if (i < W_TOTAL + NBIAS) {
    float* wsF = (float*)(ws + W_TOTAL);
    int o = i - W_TOTAL;
    float acc = 0.f;
    if (o < 192) {                          // bq'/bk'/bv' = W{q,k,v}@bp + inpb
      int mat = o >> 6, e = o & 63;
      const float* wr = inpw + (mat * 64 + e) * 64;
      for (int c = 0; c < 64; ++c) acc += wr[c] * bp[c];
      acc += inpb[mat * 64 + e];
      if (mat == 0) acc *= 0.25f;
    } else {                                // bih' = bih + wih_R @ bo
      int g = o - 192;
      for (int c = 0; c < 64; ++c) acc += wih[g * 128 + 64 + c] * outpb[c];
      acc += bih[g];
    }
    wsF[o] = acc;
  }
}

// Round-3 skeleton + LDS double-buffered teammate tile (T14 pipeline).
// LDS 76800 B -> still 2 blocks/CU (81920 cap); (256,2) keeps VGPR cap at 256
// so the reg-staged tile (live ~160 VGPR) cannot spill (round-1/2 lesson).
__global__ __launch_bounds__(256, 2)
void aerial_main(const float* __restrict__ obs, const float* __restrict__ pb,
                 const float* __restrict__ th,
                 const float* __restrict__ b1, const float* __restrict__ b2,
                 const float* __restrict__ bpol, const float* __restrict__ bhh,
                 const u16* __restrict__ wsb,
                 float* __restrict__ outLog, float* __restrict__ outBel,
                 float* __restrict__ outAttn) {
  // strides 132/68: word-stride 66/34 -> bank step 2 -> 2-way aliasing (free)
  __shared__ u16 bufP[64 * 132];   // prev_belief bf16 (persists to GRU)
  __shared__ u16 bufT0[64 * 132];  // obs -> odd tiles -> belief
  __shared__ u16 bufT1[64 * 132];  // even tiles
  __shared__ u16 bufH1[64 * 68];   // t1 -> v -> ctx
  __shared__ u16 bufHO[64 * 68];   // h_obs (persists to GRU)
  __shared__ u16 bufQ[64 * 68];    // q -> k

  const int tid   = threadIdx.x;
  const int lane  = tid & 63;
  const int m     = lane & 31;
  const int half  = lane >> 5;
  const int khalf = half * 8;
  const int wv    = tid >> 6;
  const int mt    = wv & 1;        // M-tile (rows 32*mt..)
  const int nh    = wv >> 1;       // N-half
  const int aRow  = 32 * mt + m;
  const int rowOff = 32 * mt + 4 * half;
  const int col64 = nh * 32 + m;   // column in 64-wide stages
  const int gRow0 = blockIdx.x * 64;

  const float* wsF = (const float*)(wsb + W_TOTAL);

  // stage 64x128 f32 tile -> bf16 LDS (stride 132), coalesced float4 (immediate)
  auto stage = [&](const float* src, int srcStride, u16* dst) {
#pragma unroll
    for (int i = 0; i < 8; ++i) {
      int f4 = tid + i * 256;          // 0..2047
      int row = f4 >> 5;               // 32 float4 per row
      int c4  = f4 & 31;
      float4 v = *(const float4*)(src + (size_t)row * srcStride + c4 * 4);
      ushort4 o;
      o.x = f2bf(v.x); o.y = f2bf(v.y); o.z = f2bf(v.z); o.w = f2bf(v.w);
      *(ushort4*)(dst + row * 132 + c4 * 4) = o;
    }
  };

  // reg-staged teammate tile: issue -> (compute overlaps) -> swrite next iter
  float4 sreg[8];
  auto issue = [&](int t) {
#pragma unroll
    for (int i = 0; i < 8; ++i) {
      int f4 = tid + i * 256;
      int row = f4 >> 5, c4 = f4 & 31;
      sreg[i] = *(const float4*)(th + ((size_t)(gRow0 + row) * NT + t) * HD_ + c4 * 4);
    }
  };
  auto swrite = [&](u16* dst) {
#pragma unroll
    for (int i = 0; i < 8; ++i) {
      int f4 = tid + i * 256;
      int row = f4 >> 5, c4 = f4 & 31;
      ushort4 o;
      o.x = f2bf(sreg[i].x); o.y = f2bf(sreg[i].y);
      o.z = f2bf(sreg[i].z); o.w = f2bf(sreg[i].w);
      *(ushort4*)(dst + row * 132 + c4 * 4) = o;
    }
  };

  // ---- prologue: stage obs+pb; tile0 loads in flight under A1/Q' ----
  issue(0);
  stage(obs + (size_t)gRow0 * OBSD, OBSD, bufT0);
  stage(pb  + (size_t)gRow0 * HD_,  HD_,  bufP);
  __syncthreads();

  { // A1: relu(obs @ W1^T + b1) -> t1
    f32x16 acc = gemm_acc<8>(bufT0, 132, aRow, khalf, wsb + OFF_W1 + col64 * 128, zero16());
    epiLDS(acc, b1[col64], rowOff, col64, bufH1, 68, true);
  }
  { // Q': pb @ WQP^T + bq'  (Wp, Wq and 0.25 scale all folded) -> q
    f32x16 acc = gemm_acc<8>(bufP, 132, aRow, khalf, wsb + OFF_WQP + col64 * 128, zero16());
    epiLDS(acc, wsF[col64], rowOff, col64, bufQ, 68, false);
  }
  swrite(bufT1);                       // tile0 -> bufT1 (even tiles)
  __syncthreads();

  { // A2: relu(t1 @ W2^T + b2) -> h_obs
    f32x16 acc = gemm_acc<4>(bufH1, 68, aRow, khalf, wsb + OFF_W2 + col64 * 64, zero16());
    epiLDS(acc, b2[col64], rowOff, col64, bufHO, 68, true);
  }
  // q -> regs (loop's sync_A orders these reads vs iter-0's k-writes)
  const int b  = tid >> 2;             // attention thread = (row, head)
  const int hh = tid & 3;
  float qreg[16];
  rd16(bufQ + b * 68 + hh * 16, qreg);
  issue(1);                            // tile1 loads in flight across sync_A + MFMAs

  const u16* bKp = wsb + OFF_WKP + col64 * 128 + khalf;
  const u16* bVp = wsb + OFF_WVP + col64 * 128 + khalf;
  const float bkF = wsF[64 + col64];
  const float bvF = wsF[128 + col64];
  float ctx[16];
#pragma unroll
  for (int d = 0; d < 16; ++d) ctx[d] = 0.f;
  float l = 0.f, parr[NT];

  // ---- teammate loop: tile t in tbuf(t); sreg holds tile t+1 ----
#pragma unroll
  for (int t = 0; t < NT; ++t) {
    u16* tb = (t & 1) ? bufT0 : bufT1;       // static after full unroll
    u16* tbn = (t & 1) ? bufT1 : bufT0;
    __syncthreads();                         // sync_A: prev score done; tile t visible
    {
      bf16x8 af[8];
#pragma unroll
      for (int ks = 0; ks < 8; ++ks) af[ks] = ldsA(tb + aRow * 132 + ks * 16 + khalf);
      f32x16 aK = zero16(), aV = zero16();
#pragma unroll
      for (int ks = 0; ks < 8; ++ks) {       // two independent 8-deep chains
        aK = mfma(af[ks], *(const bf16x8*)(bKp + ks * 16), aK);
        aV = mfma(af[ks], *(const bf16x8*)(bVp + ks * 16), aV);
      }
      epiLDS(aK, bkF, rowOff, col64, bufQ, 68, false);   // k
      epiLDS(aV, bvF, rowOff, col64, bufH1, 68, false);  // v
    }
    if (t + 1 < NT) swrite(tbn);             // tile t+1 -> other buffer (no race:
                                             // its last readers sync'd at sync_A)
    __syncthreads();                         // sync_B: k/v (+tile t+1) visible
    if (t + 2 < NT) issue(t + 2);            // loads span score + sync_A + MFMAs
    { // score + PV (|s| small -> exp w/o max-subtraction is exact)
      float kv[16];
      rd16(bufQ + b * 68 + hh * 16, kv);
      float s = 0.f;
#pragma unroll
      for (int d = 0; d < 16; ++d) s += qreg[d] * kv[d];
      float p = __expf(s);
      l += p; parr[t] = p;
      rd16(bufH1 + b * 68 + hh * 16, kv);
#pragma unroll
      for (int d = 0; d < 16; ++d) ctx[d] += p * kv[d];
    }
  }

  { // attn_weights (mean over heads) + normalized ctx -> bufH1
    // (each thread overwrites exactly the addresses it just read -> no race)
    float linv = 1.f / l;
#pragma unroll
    for (int t = 0; t < NT; ++t) {
      float a = parr[t] * linv;
      a += __shfl_xor(a, 1);
      a += __shfl_xor(a, 2);
      if (hh == 0) outAttn[(size_t)(gRow0 + b) * NT + t] = a * 0.25f;
    }
#pragma unroll
    for (int d = 0; d < 16; ++d) bufH1[b * 68 + hh * 16 + d] = f2bf(ctx[d] * linv);
  }
  __syncthreads();

  // ---- GRU (out_proj folded into wih'): gates via MFMA, epilogue in-register ----
  bf16x8 ax[8], apb[8];                // x = [h_obs | ctx], pb
#pragma unroll
  for (int ks = 0; ks < 4; ++ks) ax[ks]     = ldsA(bufHO + aRow * 68 + ks * 16 + khalf);
#pragma unroll
  for (int ks = 0; ks < 4; ++ks) ax[4 + ks] = ldsA(bufH1 + aRow * 68 + ks * 16 + khalf);
#pragma unroll
  for (int ks = 0; ks < 8; ++ks) apb[ks]    = ldsA(bufP  + aRow * 132 + ks * 16 + khalf);

#pragma unroll
  for (int hj = 0; hj < 2; ++hj) {
    int j = nh * 32 + hj * 64 + m;     // gate output index 0..127
    const u16* wr = wsb + OFF_WIH + (size_t)(0 * HD_ + j) * 128;
    const u16* wz = wsb + OFF_WIH + (size_t)(1 * HD_ + j) * 128;
    const u16* wn = wsb + OFF_WIH + (size_t)(2 * HD_ + j) * 128;
    const u16* vr = wsb + OFF_WHH + (size_t)(0 * HD_ + j) * 128;
    const u16* vz = wsb + OFF_WHH + (size_t)(1 * HD_ + j) * 128;
    const u16* vn = wsb + OFF_WHH + (size_t)(2 * HD_ + j) * 128;
    f32x16 ar = zero16(), az = zero16(), ai = zero16(), ah = zero16();
#pragma unroll
    for (int ks = 0; ks < 8; ++ks) {   // 3 independent MFMA chains
      int ko = ks * 16 + khalf;
      ar = mfma(ax[ks], *(const bf16x8*)(wr + ko), ar);
      az = mfma(ax[ks], *(const bf16x8*)(wz + ko), az);
      ai = mfma(ax[ks], *(const bf16x8*)(wn + ko), ai);
    }
#pragma unroll
    for (int ks = 0; ks < 8; ++ks) {
      int ko = ks * 16 + khalf;
      ar = mfma(apb[ks], *(const bf16x8*)(vr + ko), ar);
      az = mfma(apb[ks], *(const bf16x8*)(vz + ko), az);
      ah = mfma(apb[ks], *(const bf16x8*)(vn + ko), ah);
    }
    float br_ = wsF[192 + j] + bhh[j];
    float bz_ = wsF[192 + 128 + j] + bhh[128 + j];
    float bi_ = wsF[192 + 256 + j];
    float bh_ = bhh[256 + j];
#pragma unroll
    for (int r = 0; r < 16; ++r) {
      int row = rowOff + (r & 3) + 8 * (r >> 2);
      float rr = sigf(ar[r] + br_);
      float zz = sigf(az[r] + bz_);
      float xn = ai[r] + bi_ + rr * (ah[r] + bh_);
      xn = fminf(fmaxf(xn, -15.f), 15.f);
      float tt = __expf(2.f * xn);
      float nn = (tt - 1.f) / (tt + 1.f);  // tanh
      float pv = bf2f(bufP[row * 132 + j]);
      float bel = (1.f - zz) * nn + zz * pv;
      outBel[(size_t)(gRow0 + row) * HD_ + j] = bel;
      bufT0[row * 132 + j] = f2bf(bel);    // tiles long dead
    }
  }
  __syncthreads();

  // ---- policy head (waves nh==0 only; N=16 < tile width 32) ----
  if (nh == 0) {
    int nclamp = (m < 16) ? m : 15;        // clamp B-row for lanes past N
    f32x16 acc = gemm_acc<8>(bufT0, 132, aRow, khalf, wsb + OFF_POL + nclamp * 128, zero16());
    if (m < 16) {
      float bv = bpol[m];
#pragma unroll
      for (int r = 0; r < 16; ++r) {
        int row = rowOff + (r & 3) + 8 * (r >> 2);
        outLog[(size_t)(gRow0 + row) * NA + m] = acc[r] + bv;
      }
    }
  }
}

extern "C" void kernel_launch(void* const* d_in, const int* in_sizes, int n_in,
                              void* d_out, int out_size, void* d_ws, size_t ws_size,
                              hipStream_t stream) {
  const float* obs   = (const float*)d_in[0];
  const float* pb    = (const float*)d_in[1];
  const float* th    = (const float*)d_in[2];
  const float* W1    = (const float*)d_in[3];
  const float* b1    = (const float*)d_in[4];
  const float* W2    = (const float*)d_in[5];
  const float* b2    = (const float*)d_in[6];
  const float* Wp    = (const float*)d_in[7];
  const float* bp    = (const float*)d_in[8];
  const float* inpw  = (const float*)d_in[9];
  const float* inpb  = (const float*)d_in[10];
  const float* outpw = (const float*)d_in[11];
  const float* outpb = (const float*)d_in[12];
  const float* wih   = (const float*)d_in[13];
  const float* whh   = (const float*)d_in[14];
  const float* bih   = (const float*)d_in[15];
  const float* bhh   = (const float*)d_in[16];
  const float* wpol  = (const float*)d_in[17];
  const float* bpol  = (const float*)d_in[18];

  u16* wsb = (u16*)d_ws;                     // 274432 B bf16 weights + 2304 B f32 biases
  float* outLog  = (float*)d_out;
  float* outBel  = outLog + (size_t)NB * NA;
  float* outAttn = outBel + (size_t)NB * HD_;

  prep_weights<<<(W_TOTAL + NBIAS + 255) / 256, 256, 0, stream>>>(
      W1, W2, Wp, bp, inpw, inpb, outpw, outpb, wih, bih, whh, wpol, wsb);
  aerial_main<<<NB / 64, 256, 0, stream>>>(obs, pb, th, b1, b2, bpol, bhh, wsb,
                                           outLog, outBel, outAttn);
}